// Round 1
// baseline (184.352 us; speedup 1.0000x reference)
//
#include <hip/hip_runtime.h>
#include <math.h>

#define DIM 4096
#define BATCH 64

#define K2_RB 128
#define K2_KS 8
#define K2_KC (DIM / K2_KS)   // 512 k per block
#define K2_BK 64              // staged sub-chunk

__device__ __forceinline__ float4 ld4(const float* p) {
    return *reinterpret_cast<const float4*>(p);
}

// K1: L2-normalize rows of input_x -> xn [BATCH][DIM] and xnT [DIM][BATCH]
__global__ __launch_bounds__(256) void k_norm(const float* __restrict__ x,
                                              float* __restrict__ xn,
                                              float* __restrict__ xnT) {
    const int b = blockIdx.x;
    const int tid = threadIdx.x;
    const float* row = x + (size_t)b * DIM;

    float ss = 0.f;
    for (int k = tid * 4; k < DIM; k += 256 * 4) {
        float4 v = ld4(row + k);
        ss += v.x * v.x + v.y * v.y + v.z * v.z + v.w * v.w;
    }
#pragma unroll
    for (int m = 32; m >= 1; m >>= 1) ss += __shfl_xor(ss, m, 64);

    __shared__ float wsum[4];
    if ((tid & 63) == 0) wsum[tid >> 6] = ss;
    __syncthreads();
    const float total = wsum[0] + wsum[1] + wsum[2] + wsum[3];
    const float scale = 1.0f / (sqrtf(total) + 1e-8f);

    for (int k = tid * 4; k < DIM; k += 256 * 4) {
        float4 v = ld4(row + k);
        v.x *= scale; v.y *= scale; v.z *= scale; v.w *= scale;
        *reinterpret_cast<float4*>(xn + (size_t)b * DIM + k) = v;
        xnT[(size_t)(k + 0) * BATCH + b] = v.x;
        xnT[(size_t)(k + 1) * BATCH + b] = v.y;
        xnT[(size_t)(k + 2) * BATCH + b] = v.z;
        xnT[(size_t)(k + 3) * BATCH + b] = v.w;
    }
}

// K2: ypart[ks] = W[i0:i0+128, k0:k0+512] @ xnT[k0:k0+512, :]   (split-K partials)
__global__ __launch_bounds__(256) void k_wxt(const float* __restrict__ W,
                                             const float* __restrict__ xnT,
                                             float* __restrict__ ypart) {
    __shared__ float As[K2_BK][K2_RB + 4];   // [kk][i], transposed, padded
    __shared__ float Xs[K2_BK][BATCH];       // [kk][b]

    const int i0 = blockIdx.x * K2_RB;
    const int k0 = blockIdx.y * K2_KC;
    const int tid = threadIdx.x;
    const int ci = tid & 15;   // i-group: rows ci*8 .. ci*8+7
    const int cb = tid >> 4;   // b-group: cols cb*4 .. cb*4+3

    float acc[8][4] = {};

    for (int kc = 0; kc < K2_KC; kc += K2_BK) {
        const int kb = k0 + kc;
        // stage A transposed: 128 rows x 64 k (coalesced global read)
        {
            const int fr = tid >> 4;   // 0..15
            const int fc = tid & 15;   // 0..15 (float4 groups along k)
#pragma unroll
            for (int p = 0; p < 8; ++p) {
                const int r = fr + p * 16;
                float4 v = ld4(W + (size_t)(i0 + r) * DIM + kb + fc * 4);
                As[fc * 4 + 0][r] = v.x;
                As[fc * 4 + 1][r] = v.y;
                As[fc * 4 + 2][r] = v.z;
                As[fc * 4 + 3][r] = v.w;
            }
        }
        // stage X: contiguous copy of xnT chunk
        {
            const float4* src = reinterpret_cast<const float4*>(xnT + (size_t)kb * BATCH);
            float4* dst = reinterpret_cast<float4*>(&Xs[0][0]);
#pragma unroll
            for (int q = 0; q < 4; ++q) dst[tid + q * 256] = src[tid + q * 256];
        }
        __syncthreads();

#pragma unroll 4
        for (int kk = 0; kk < K2_BK; ++kk) {
            float4 a0 = ld4(&As[kk][ci * 8]);
            float4 a1 = ld4(&As[kk][ci * 8 + 4]);
            float4 xq = ld4(&Xs[kk][cb * 4]);
            float a[8] = {a0.x, a0.y, a0.z, a0.w, a1.x, a1.y, a1.z, a1.w};
            float xv[4] = {xq.x, xq.y, xq.z, xq.w};
#pragma unroll
            for (int r = 0; r < 8; ++r)
#pragma unroll
                for (int c = 0; c < 4; ++c)
                    acc[r][c] += a[r] * xv[c];
        }
        __syncthreads();
    }

    float* yp = ypart + (size_t)blockIdx.y * DIM * BATCH;
#pragma unroll
    for (int r = 0; r < 8; ++r) {
        float4 v = {acc[r][0], acc[r][1], acc[r][2], acc[r][3]};
        *reinterpret_cast<float4*>(yp + (size_t)(i0 + ci * 8 + r) * BATCH + cb * 4) = v;
    }
}

// K2.5: y = sum over split-K partials (deterministic, no atomics)
__global__ __launch_bounds__(256) void k_reduce(const float* __restrict__ ypart,
                                                float* __restrict__ y) {
    const int idx = blockIdx.x * 256 + threadIdx.x;  // over DIM*BATCH/4 float4
    const float4* p = reinterpret_cast<const float4*>(ypart);
    float4 s = p[idx];
#pragma unroll
    for (int q = 1; q < K2_KS; ++q) {
        float4 v = p[(size_t)q * (DIM * BATCH / 4) + idx];
        s.x += v.x; s.y += v.y; s.z += v.z; s.w += v.w;
    }
    reinterpret_cast<float4*>(y)[idx] = s;
}

// K3: out = W - lr*G - c * (y @ xn)  -- rank-64 update, no LDS (y/xn are L2-hot)
__global__ __launch_bounds__(256) void k_update(const float* __restrict__ W,
                                                const float* __restrict__ G,
                                                const float* __restrict__ y,
                                                const float* __restrict__ xn,
                                                float* __restrict__ out) {
    const int i0 = blockIdx.x * 128;
    const int j0 = blockIdx.y * 128;
    const int tid = threadIdx.x;
    const int ci = tid & 15;
    const int cj = tid >> 4;
    const int ib = i0 + ci * 8;
    const int jb = j0 + cj * 8;

    float acc[8][8] = {};

    for (int bq = 0; bq < BATCH / 4; ++bq) {
        float4 yv[8];
#pragma unroll
        for (int r = 0; r < 8; ++r)
            yv[r] = ld4(y + (size_t)(ib + r) * BATCH + bq * 4);
#pragma unroll
        for (int j = 0; j < 4; ++j) {
            const int b = bq * 4 + j;
            float4 x0 = ld4(xn + (size_t)b * DIM + jb);
            float4 x1 = ld4(xn + (size_t)b * DIM + jb + 4);
            float xv[8] = {x0.x, x0.y, x0.z, x0.w, x1.x, x1.y, x1.z, x1.w};
#pragma unroll
            for (int r = 0; r < 8; ++r) {
                const float yb = (j == 0) ? yv[r].x : (j == 1) ? yv[r].y
                               : (j == 2) ? yv[r].z : yv[r].w;
#pragma unroll
                for (int c = 0; c < 8; ++c) acc[r][c] += yb * xv[c];
            }
        }
    }

    constexpr float C  = 0.01f / 64.0f;   // alpha / batch
    constexpr float LR = 0.001f;
#pragma unroll
    for (int r = 0; r < 8; ++r) {
        const size_t base = (size_t)(ib + r) * DIM + jb;
#pragma unroll
        for (int c4 = 0; c4 < 2; ++c4) {
            float4 w = ld4(W + base + c4 * 4);
            float4 g = ld4(G + base + c4 * 4);
            float4 o;
            o.x = w.x - LR * g.x - C * acc[r][c4 * 4 + 0];
            o.y = w.y - LR * g.y - C * acc[r][c4 * 4 + 1];
            o.z = w.z - LR * g.z - C * acc[r][c4 * 4 + 2];
            o.w = w.w - LR * g.w - C * acc[r][c4 * 4 + 3];
            *reinterpret_cast<float4*>(out + base + c4 * 4) = o;
        }
    }
}

extern "C" void kernel_launch(void* const* d_in, const int* in_sizes, int n_in,
                              void* d_out, int out_size, void* d_ws, size_t ws_size,
                              hipStream_t stream) {
    const float* W = (const float*)d_in[0];   // weight  (DIM x DIM)
    const float* X = (const float*)d_in[1];   // input_x (BATCH x DIM)
    const float* G = (const float*)d_in[2];   // grad    (DIM x DIM)
    float* out = (float*)d_out;

    float* ws    = (float*)d_ws;
    float* xn    = ws;                               // BATCH*DIM      (1 MB)
    float* xnT   = xn  + (size_t)BATCH * DIM;        // DIM*BATCH      (1 MB)
    float* y     = xnT + (size_t)DIM * BATCH;        // DIM*BATCH      (1 MB)
    float* ypart = y   + (size_t)DIM * BATCH;        // K2_KS*DIM*BATCH (8 MB)

    hipLaunchKernelGGL(k_norm, dim3(BATCH), dim3(256), 0, stream, X, xn, xnT);
    hipLaunchKernelGGL(k_wxt, dim3(DIM / K2_RB, K2_KS), dim3(256), 0, stream,
                       W, xnT, ypart);
    hipLaunchKernelGGL(k_reduce, dim3(DIM * BATCH / 4 / 256), dim3(256), 0, stream,
                       ypart, y);
    hipLaunchKernelGGL(k_update, dim3(DIM / 128, DIM / 128), dim3(256), 0, stream,
                       W, G, y, xn, out);
}

// Round 2
// 151.497 us; speedup vs baseline: 1.2169x; 1.2169x over previous
//
#include <hip/hip_runtime.h>
#include <math.h>

#define DIM 4096
#define BATCH 64

__device__ __forceinline__ float4 ld4(const float* p) {
    return *reinterpret_cast<const float4*>(p);
}

// K1: L2-normalize rows of input_x -> xn [BATCH][DIM] and xnT [DIM][BATCH]
__global__ __launch_bounds__(256) void k_norm(const float* __restrict__ x,
                                              float* __restrict__ xn,
                                              float* __restrict__ xnT) {
    const int b = blockIdx.x;
    const int tid = threadIdx.x;
    const float* row = x + (size_t)b * DIM;

    float ss = 0.f;
    for (int k = tid * 4; k < DIM; k += 256 * 4) {
        float4 v = ld4(row + k);
        ss += v.x * v.x + v.y * v.y + v.z * v.z + v.w * v.w;
    }
#pragma unroll
    for (int m = 32; m >= 1; m >>= 1) ss += __shfl_xor(ss, m, 64);

    __shared__ float wsum[4];
    if ((tid & 63) == 0) wsum[tid >> 6] = ss;
    __syncthreads();
    const float total = wsum[0] + wsum[1] + wsum[2] + wsum[3];
    const float scale = 1.0f / (sqrtf(total) + 1e-8f);

    for (int k = tid * 4; k < DIM; k += 256 * 4) {
        float4 v = ld4(row + k);
        v.x *= scale; v.y *= scale; v.z *= scale; v.w *= scale;
        *reinterpret_cast<float4*>(xn + (size_t)b * DIM + k) = v;
        xnT[(size_t)(k + 0) * BATCH + b] = v.x;
        xnT[(size_t)(k + 1) * BATCH + b] = v.y;
        xnT[(size_t)(k + 2) * BATCH + b] = v.z;
        xnT[(size_t)(k + 3) * BATCH + b] = v.w;
    }
}

// K2: ypart[ks] = W[i0:i0+128, k0:k0+KC] @ xnT[k0:k0+KC, :]   (split-K partials)
// grid = (DIM/128, KS); KC = DIM/KS (runtime, multiple of 64)
__global__ __launch_bounds__(256, 4) void k_wxt(const float* __restrict__ W,
                                                const float* __restrict__ xnT,
                                                float* __restrict__ ypart,
                                                int KC) {
    __shared__ float As[64][128 + 4];   // [kk][i], transposed, padded
    __shared__ float Xs[64][BATCH];     // [kk][b]

    const int i0 = blockIdx.x * 128;
    const int k0 = blockIdx.y * KC;
    const int tid = threadIdx.x;
    const int ci = tid & 15;   // i-group: rows ci*8 .. ci*8+7
    const int cb = tid >> 4;   // b-group: cols cb*4 .. cb*4+3

    float acc[8][4] = {};

    for (int kc = 0; kc < KC; kc += 64) {
        const int kb = k0 + kc;
        // stage A transposed: 128 rows x 64 k (coalesced global read)
        {
            const int fr = tid >> 4;   // 0..15
            const int fc = tid & 15;   // 0..15 (float4 groups along k)
#pragma unroll
            for (int p = 0; p < 8; ++p) {
                const int r = fr + p * 16;
                float4 v = ld4(W + (size_t)(i0 + r) * DIM + kb + fc * 4);
                As[fc * 4 + 0][r] = v.x;
                As[fc * 4 + 1][r] = v.y;
                As[fc * 4 + 2][r] = v.z;
                As[fc * 4 + 3][r] = v.w;
            }
        }
        // stage X: contiguous copy of xnT chunk
        {
            const float4* src = reinterpret_cast<const float4*>(xnT + (size_t)kb * BATCH);
            float4* dst = reinterpret_cast<float4*>(&Xs[0][0]);
#pragma unroll
            for (int q = 0; q < 4; ++q) dst[tid + q * 256] = src[tid + q * 256];
        }
        __syncthreads();

#pragma unroll 4
        for (int kk = 0; kk < 64; ++kk) {
            float4 a0 = ld4(&As[kk][ci * 8]);
            float4 a1 = ld4(&As[kk][ci * 8 + 4]);
            float4 xq = ld4(&Xs[kk][cb * 4]);
            float a[8] = {a0.x, a0.y, a0.z, a0.w, a1.x, a1.y, a1.z, a1.w};
            float xv[4] = {xq.x, xq.y, xq.z, xq.w};
#pragma unroll
            for (int r = 0; r < 8; ++r)
#pragma unroll
                for (int c = 0; c < 4; ++c)
                    acc[r][c] += a[r] * xv[c];
        }
        __syncthreads();
    }

    float* yp = ypart + (size_t)blockIdx.y * DIM * BATCH;
#pragma unroll
    for (int r = 0; r < 8; ++r) {
        float4 v = {acc[r][0], acc[r][1], acc[r][2], acc[r][3]};
        *reinterpret_cast<float4*>(yp + (size_t)(i0 + ci * 8 + r) * BATCH + cb * 4) = v;
    }
}

// K2.5: y = sum over split-K partials (deterministic, no atomics)
__global__ __launch_bounds__(256) void k_reduce(const float* __restrict__ ypart,
                                                float* __restrict__ y, int ks) {
    const int idx = blockIdx.x * 256 + threadIdx.x;  // over DIM*BATCH/4 float4
    const float4* p = reinterpret_cast<const float4*>(ypart);
    float4 s = p[idx];
    for (int q = 1; q < ks; ++q) {
        float4 v = p[(size_t)q * (DIM * BATCH / 4) + idx];
        s.x += v.x; s.y += v.y; s.z += v.z; s.w += v.w;
    }
    reinterpret_cast<float4*>(y)[idx] = s;
}

// K3: out = W - lr*G - c * (y @ xn)  -- rank-64 update
// xn tile staged in LDS (conflict-free broadcast reads); y read from global
// ([row][batch] float4 loads, 16-lane broadcast, L1/L2-resident).
__global__ __launch_bounds__(256, 3) void k_update(const float* __restrict__ W,
                                                   const float* __restrict__ G,
                                                   const float* __restrict__ y,
                                                   const float* __restrict__ xn,
                                                   float* __restrict__ out) {
    __shared__ float xlds[BATCH][128 + 4];   // row stride 132 floats (16B-aligned, bank-rotating)

    const int i0 = blockIdx.x * 128;
    const int j0 = blockIdx.y * 128;
    const int tid = threadIdx.x;
    const int ci = tid & 15;   // row group
    const int cj = tid >> 4;   // col group
    const int ib = i0 + ci * 8;
    const int jb = cj * 8;

    // stage xn[0..64][j0..j0+128] -> xlds (2048 float4s, 8 per thread, coalesced)
    {
        const int r = tid >> 2;    // 0..63 (row)
        const int c = tid & 3;     // float4 slot base
#pragma unroll
        for (int q = 0; q < 8; ++q) {
            const int g = c + q * 4;     // float4 group 0..31
            float4 v = ld4(xn + (size_t)r * DIM + j0 + g * 4);
            *reinterpret_cast<float4*>(&xlds[r][g * 4]) = v;
        }
    }
    __syncthreads();

    float acc[8][8] = {};

    for (int bq = 0; bq < BATCH / 4; ++bq) {
        float4 yv[8];
#pragma unroll
        for (int r = 0; r < 8; ++r)
            yv[r] = ld4(y + (size_t)(ib + r) * BATCH + bq * 4);
#pragma unroll
        for (int j = 0; j < 4; ++j) {
            const int b = bq * 4 + j;
            float4 x0 = *reinterpret_cast<const float4*>(&xlds[b][jb]);
            float4 x1 = *reinterpret_cast<const float4*>(&xlds[b][jb + 4]);
            float xv[8] = {x0.x, x0.y, x0.z, x0.w, x1.x, x1.y, x1.z, x1.w};
#pragma unroll
            for (int r = 0; r < 8; ++r) {
                const float yb = (j == 0) ? yv[r].x : (j == 1) ? yv[r].y
                               : (j == 2) ? yv[r].z : yv[r].w;
#pragma unroll
                for (int c = 0; c < 8; ++c) acc[r][c] += yb * xv[c];
            }
        }
    }

    constexpr float C  = 0.01f / 64.0f;   // alpha / batch
    constexpr float LR = 0.001f;
#pragma unroll
    for (int r = 0; r < 8; ++r) {
        const size_t base = (size_t)(ib + r) * DIM + j0 + jb;
#pragma unroll
        for (int c4 = 0; c4 < 2; ++c4) {
            float4 w = ld4(W + base + c4 * 4);
            float4 g = ld4(G + base + c4 * 4);
            float4 o;
            o.x = w.x - LR * g.x - C * acc[r][c4 * 4 + 0];
            o.y = w.y - LR * g.y - C * acc[r][c4 * 4 + 1];
            o.z = w.z - LR * g.z - C * acc[r][c4 * 4 + 2];
            o.w = w.w - LR * g.w - C * acc[r][c4 * 4 + 3];
            *reinterpret_cast<float4*>(out + base + c4 * 4) = o;
        }
    }
}

extern "C" void kernel_launch(void* const* d_in, const int* in_sizes, int n_in,
                              void* d_out, int out_size, void* d_ws, size_t ws_size,
                              hipStream_t stream) {
    const float* W = (const float*)d_in[0];   // weight  (DIM x DIM)
    const float* X = (const float*)d_in[1];   // input_x (BATCH x DIM)
    const float* G = (const float*)d_in[2];   // grad    (DIM x DIM)
    float* out = (float*)d_out;

    // split-K factor for k_wxt, bounded by workspace size
    const size_t MB = 1024 * 1024;
    const size_t fixed = 3 * MB;                     // xn + xnT + y
    int KS = 8;
    if (ws_size >= fixed + 32 * MB + MB) KS = 32;
    else if (ws_size >= fixed + 16 * MB + MB) KS = 16;
    const int KC = DIM / KS;

    float* ws    = (float*)d_ws;
    float* xn    = ws;                               // BATCH*DIM      (1 MB)
    float* xnT   = xn  + (size_t)BATCH * DIM;        // DIM*BATCH      (1 MB)
    float* y     = xnT + (size_t)DIM * BATCH;        // DIM*BATCH      (1 MB)
    float* ypart = y   + (size_t)DIM * BATCH;        // KS*DIM*BATCH

    hipLaunchKernelGGL(k_norm, dim3(BATCH), dim3(256), 0, stream, X, xn, xnT);
    hipLaunchKernelGGL(k_wxt, dim3(DIM / 128, KS), dim3(256), 0, stream,
                       W, xnT, ypart, KC);
    hipLaunchKernelGGL(k_reduce, dim3(DIM * BATCH / 4 / 256), dim3(256), 0, stream,
                       ypart, y, KS);
    hipLaunchKernelGGL(k_update, dim3(DIM / 128, DIM / 128), dim3(256), 0, stream,
                       W, G, y, xn, out);
}

// Round 3
// 61.410 us; speedup vs baseline: 3.0020x; 2.4670x over previous
//
#include <hip/hip_runtime.h>
#include <math.h>

#define DIM 4096
#define BATCH 64

typedef __attribute__((ext_vector_type(8))) short short8;
typedef __attribute__((ext_vector_type(4))) float f32x4;

__device__ __forceinline__ float4 ld4(const float* p) {
    return *reinterpret_cast<const float4*>(p);
}

// f32 -> bf16 bits, round-to-nearest-even (values are normal, no NaN handling)
__device__ __forceinline__ unsigned short f2bf(float f) {
    unsigned u = __builtin_bit_cast(unsigned, f);
    u = (u + 0x7fffu + ((u >> 16) & 1u)) >> 16;
    return (unsigned short)u;
}

// K1: L2-normalize rows of input_x; emit bf16 in MFMA B-fragment order.
//
// MFMA 16x16x32 bf16 fragment convention (verified layouts, learn_hip m89):
//   A: lane l, reg j  -> A[l&15][(l>>4)*8 + j]
//   B: lane l, reg j  -> B[(l>>4)*8 + j][l&15]
//   D: lane l, reg q  -> D[(l>>4)*4 + q][l&15]
//
// xb1: B for phase 1 (y = W @ xnT), K-dim = k, col = b.
//   element (k,b) -> short8-slot (b>>4)*8192 + (k>>5)*64 + ((b&15) | (((k&31)>>3)<<4)), elem k&7
// xb2: B for phase 2 (corr = y @ xn), K-dim = b, col = j.
//   element (b,j) -> short8-slot ((j>>4)*2 + (b>>5))*64 + ((j&15) | (((b&31)>>3)<<4)), elem b&7
__global__ __launch_bounds__(256) void k_norm(const float* __restrict__ x,
                                              unsigned short* __restrict__ xb1,
                                              unsigned short* __restrict__ xb2) {
    const int b = blockIdx.x;
    const int tid = threadIdx.x;
    const float* row = x + (size_t)b * DIM;

    float ss = 0.f;
    for (int k = tid * 4; k < DIM; k += 256 * 4) {
        float4 v = ld4(row + k);
        ss += v.x * v.x + v.y * v.y + v.z * v.z + v.w * v.w;
    }
#pragma unroll
    for (int m = 32; m >= 1; m >>= 1) ss += __shfl_xor(ss, m, 64);

    __shared__ float wsum[4];
    if ((tid & 63) == 0) wsum[tid >> 6] = ss;
    __syncthreads();
    const float total = wsum[0] + wsum[1] + wsum[2] + wsum[3];
    const float scale = 1.0f / (sqrtf(total) + 1e-8f);

    const int bt = b >> 4;            // xb1 b-tile
    const int li = b & 15;            // xb1 col-in-tile
    const int ks = b >> 5;            // xb2 K-step
    const int hi = (b & 31) >> 3;     // xb2 lane-high bits
    const int jr = b & 7;             // xb2 reg index

    for (int k = tid; k < DIM; k += 256) {
        const float v = row[k] * scale;
        const unsigned short h = f2bf(v);
        // xb1 (k is the K-dim)
        const int l1 = li | (((k & 31) >> 3) << 4);
        xb1[(size_t)((((bt * 128) + (k >> 5)) * 64 + l1) << 3) + (k & 7)] = h;
        // xb2 (k is the column dim j; b is the K-dim)
        const int l2 = (k & 15) | (hi << 4);
        xb2[(size_t)(((((k >> 4) * 2) + ks) * 64 + l2) << 3) + jr] = h;
    }
}

// Fused: per 16-row tile of W:
//   phase 1: y[16][64] = W_rows @ xnT   (split-K over 16 waves, MFMA, LDS-reduce)
//   phase 2: out_rows = W - lr*G + (-alpha/B * y) @ xn   (MFMA rank-64 + stream epilogue)
__global__ __launch_bounds__(1024, 4) void k_fused(const float* __restrict__ W,
                                                   const float* __restrict__ G,
                                                   const unsigned short* __restrict__ xb1,
                                                   const unsigned short* __restrict__ xb2,
                                                   float* __restrict__ out) {
    __shared__ float yp[16 * 4 * 64 * 4];   // per-wave partial D-tiles, 64 KB
    __shared__ float y2[16 * 68];           // reduced y[16][64], padded

    const int tid = threadIdx.x;
    const int wv = tid >> 6;      // wave 0..15
    const int l  = tid & 63;      // lane
    const int lr = l & 15;
    const int lh = l >> 4;
    const int i0 = blockIdx.x * 16;

    // ---------------- phase 1: y = W_rows @ xnT, wave wv covers K in [wv*256, wv*256+256)
    f32x4 acc0 = {0.f, 0.f, 0.f, 0.f};
    f32x4 acc1 = acc0, acc2 = acc0, acc3 = acc0;

    const short8* xb1v = (const short8*)xb1;   // short8 granularity
#pragma unroll
    for (int kb8 = 0; kb8 < 8; ++kb8) {
        const int kbg = wv * 8 + kb8;          // global K-step (32 wide), 0..127
        const float* wp = W + (size_t)(i0 + lr) * DIM + kbg * 32 + lh * 8;
        const float4 wa = ld4(wp);
        const float4 wb = ld4(wp + 4);
        short8 a;
        a[0] = (short)f2bf(wa.x); a[1] = (short)f2bf(wa.y);
        a[2] = (short)f2bf(wa.z); a[3] = (short)f2bf(wa.w);
        a[4] = (short)f2bf(wb.x); a[5] = (short)f2bf(wb.y);
        a[6] = (short)f2bf(wb.z); a[7] = (short)f2bf(wb.w);
        const int bslot = kbg * 64 + l;
        acc0 = __builtin_amdgcn_mfma_f32_16x16x32_bf16(a, xb1v[bslot         ], acc0, 0, 0, 0);
        acc1 = __builtin_amdgcn_mfma_f32_16x16x32_bf16(a, xb1v[bslot + 8192  ], acc1, 0, 0, 0);
        acc2 = __builtin_amdgcn_mfma_f32_16x16x32_bf16(a, xb1v[bslot + 16384 ], acc2, 0, 0, 0);
        acc3 = __builtin_amdgcn_mfma_f32_16x16x32_bf16(a, xb1v[bslot + 24576 ], acc3, 0, 0, 0);
    }
    {
        f32x4* dst = (f32x4*)yp;
        dst[(wv * 4 + 0) * 64 + l] = acc0;
        dst[(wv * 4 + 1) * 64 + l] = acc1;
        dst[(wv * 4 + 2) * 64 + l] = acc2;
        dst[(wv * 4 + 3) * 64 + l] = acc3;
    }
    __syncthreads();

    // reduce 16 partials: thread t owns y element (r = t>>6, b = t&63)
    {
        const int r  = tid >> 6;
        const int bb = tid & 63;
        const int btt = bb >> 4;
        const int lii = (bb & 15) | ((r >> 2) << 4);
        const int jq  = r & 3;
        float s = 0.f;
#pragma unroll
        for (int w = 0; w < 16; ++w) s += yp[((w * 4 + btt) * 64 + lii) * 4 + jq];
        y2[r * 68 + bb] = s;
    }
    __syncthreads();

    // ---------------- phase 2 A-fragments: ya = (-alpha/B) * y, bf16
    const float NC = -0.01f / 64.0f;
    short8 ya0, ya1;
#pragma unroll
    for (int j = 0; j < 8; ++j) {
        ya0[j] = (short)f2bf(NC * y2[lr * 68 + lh * 8 + j]);
        ya1[j] = (short)f2bf(NC * y2[lr * 68 + 32 + lh * 8 + j]);
    }

    // phase 2: wave wv owns j-tiles [wv*16, wv*16+16) -> cols [wv*256, wv*256+256)
    constexpr float LRc = 0.001f;
    const short8* xb2v = (const short8*)xb2;
#pragma unroll 4
    for (int t = 0; t < 16; ++t) {
        const int jt = wv * 16 + t;
        const int bslot = jt * 2 * 64 + l;
        f32x4 d = {0.f, 0.f, 0.f, 0.f};
        d = __builtin_amdgcn_mfma_f32_16x16x32_bf16(ya0, xb2v[bslot     ], d, 0, 0, 0);
        d = __builtin_amdgcn_mfma_f32_16x16x32_bf16(ya1, xb2v[bslot + 64], d, 0, 0, 0);
        const size_t base = (size_t)(i0 + lh * 4) * DIM + jt * 16 + lr;
#pragma unroll
        for (int q = 0; q < 4; ++q) {
            const size_t idx = base + (size_t)q * DIM;
            out[idx] = W[idx] - LRc * G[idx] + d[q];
        }
    }
}

extern "C" void kernel_launch(void* const* d_in, const int* in_sizes, int n_in,
                              void* d_out, int out_size, void* d_ws, size_t ws_size,
                              hipStream_t stream) {
    const float* W = (const float*)d_in[0];   // weight  (DIM x DIM)
    const float* X = (const float*)d_in[1];   // input_x (BATCH x DIM)
    const float* G = (const float*)d_in[2];   // grad    (DIM x DIM)
    float* out = (float*)d_out;

    unsigned short* xb1 = (unsigned short*)d_ws;               // DIM*BATCH bf16 (512 KB)
    unsigned short* xb2 = xb1 + (size_t)DIM * BATCH;           // BATCH*DIM bf16 (512 KB)

    hipLaunchKernelGGL(k_norm, dim3(BATCH), dim3(256), 0, stream, X, xb1, xb2);
    hipLaunchKernelGGL(k_fused, dim3(DIM / 16), dim3(1024), 0, stream,
                       W, G, xb1, xb2, out);
}

// Round 4
// 58.932 us; speedup vs baseline: 3.1282x; 1.0420x over previous
//
#include <hip/hip_runtime.h>
#include <math.h>

#define DIM 4096
#define BATCH 64

typedef __attribute__((ext_vector_type(8))) short short8;
typedef __attribute__((ext_vector_type(4))) float f32x4;

__device__ __forceinline__ float4 ld4(const float* p) {
    return *reinterpret_cast<const float4*>(p);
}

// f32 -> bf16 bits, round-to-nearest-even
__device__ __forceinline__ unsigned short f2bf(float f) {
    unsigned u = __builtin_bit_cast(unsigned, f);
    u = (u + 0x7fffu + ((u >> 16) & 1u)) >> 16;
    return (unsigned short)u;
}

// K1: L2-normalize rows of input_x; emit bf16 in MFMA B-fragment order.
//   B-frag: lane l, reg j -> B[(l>>4)*8 + j][l&15]
// xb1: B for phase 1 (y = W @ xnT), K-dim = k, col = b.
// xb2: B for phase 2 (corr = y @ xn), K-dim = b, col = j.
__global__ __launch_bounds__(256) void k_norm(const float* __restrict__ x,
                                              unsigned short* __restrict__ xb1,
                                              unsigned short* __restrict__ xb2) {
    const int b = blockIdx.x;
    const int tid = threadIdx.x;
    const float* row = x + (size_t)b * DIM;

    float ss = 0.f;
    for (int k = tid * 4; k < DIM; k += 256 * 4) {
        float4 v = ld4(row + k);
        ss += v.x * v.x + v.y * v.y + v.z * v.z + v.w * v.w;
    }
#pragma unroll
    for (int m = 32; m >= 1; m >>= 1) ss += __shfl_xor(ss, m, 64);

    __shared__ float wsum[4];
    if ((tid & 63) == 0) wsum[tid >> 6] = ss;
    __syncthreads();
    const float total = wsum[0] + wsum[1] + wsum[2] + wsum[3];
    const float scale = 1.0f / (sqrtf(total) + 1e-8f);

    const int bt = b >> 4;            // xb1 b-tile
    const int li = b & 15;            // xb1 col-in-tile
    const int ks = b >> 5;            // xb2 K-step
    const int hi = (b & 31) >> 3;     // xb2 lane-high bits
    const int jr = b & 7;             // xb2 reg index

    for (int k = tid; k < DIM; k += 256) {
        const float v = row[k] * scale;
        const unsigned short h = f2bf(v);
        const int l1 = li | (((k & 31) >> 3) << 4);
        xb1[(size_t)((((bt * 128) + (k >> 5)) * 64 + l1) << 3) + (k & 7)] = h;
        const int l2 = (k & 15) | (hi << 4);
        xb2[(size_t)(((((k >> 4) * 2) + ks) * 64 + l2) << 3) + jr] = h;
    }
}

// Fused: per 16-row tile of W:
//   phase 1: y[16][64] = W_rows @ xnT   (split-K over 16 waves, MFMA, LDS-reduce)
//   phase 2: out = W - lr*G + ((-alpha/B)*y) @ xn, via LDS d-transpose so the
//            streaming epilogue is fully coalesced (512B runs per row).
__global__ __launch_bounds__(1024, 4) void k_fused(const float* __restrict__ W,
                                                   const float* __restrict__ G,
                                                   const unsigned short* __restrict__ xb1,
                                                   const unsigned short* __restrict__ xb2,
                                                   float* __restrict__ out) {
    // One 132 KB buffer, reused sequentially (barriers separate the lifetimes):
    //   [0, 16384)      f32 : yp  — phase-1 per-wave partial D-tiles (64 KB)
    //   [16384, 17472)  f32 : y2  — reduced y[16][68-padded]
    //   [0, 33792)      f32 : dl  — phase-2 per-wave d-transpose (16x132 each)
    __shared__ __align__(16) float lds[33792];
    float* yp = lds;
    float* y2 = lds + 16384;

    const int tid = threadIdx.x;
    const int wv = tid >> 6;      // wave 0..15
    const int l  = tid & 63;      // lane
    const int lr = l & 15;
    const int lh = l >> 4;
    const int i0 = blockIdx.x * 16;

    // ---------------- phase 1: y = W_rows @ xnT, wave wv covers K [wv*256, +256)
    f32x4 acc0 = {0.f, 0.f, 0.f, 0.f};
    f32x4 acc1 = acc0, acc2 = acc0, acc3 = acc0;
    const short8* xb1v = (const short8*)xb1;

#pragma unroll 2
    for (int s = 0; s < 8; s += 2) {
        const int kbg = wv * 8 + s;
        const float* wp = W + (size_t)(i0 + lr) * DIM + kbg * 32 + lh * 8;
        // batch all 12 loads for 2 K-steps
        const float4 wa0 = ld4(wp);
        const float4 wb0 = ld4(wp + 4);
        const float4 wa1 = ld4(wp + 32);
        const float4 wb1 = ld4(wp + 36);
        const int bs0 = kbg * 64 + l;
        const int bs1 = bs0 + 64;
        const short8 b00 = xb1v[bs0];
        const short8 b01 = xb1v[bs0 + 8192];
        const short8 b02 = xb1v[bs0 + 16384];
        const short8 b03 = xb1v[bs0 + 24576];
        const short8 b10 = xb1v[bs1];
        const short8 b11 = xb1v[bs1 + 8192];
        const short8 b12 = xb1v[bs1 + 16384];
        const short8 b13 = xb1v[bs1 + 24576];
        short8 a0, a1;
        a0[0] = (short)f2bf(wa0.x); a0[1] = (short)f2bf(wa0.y);
        a0[2] = (short)f2bf(wa0.z); a0[3] = (short)f2bf(wa0.w);
        a0[4] = (short)f2bf(wb0.x); a0[5] = (short)f2bf(wb0.y);
        a0[6] = (short)f2bf(wb0.z); a0[7] = (short)f2bf(wb0.w);
        a1[0] = (short)f2bf(wa1.x); a1[1] = (short)f2bf(wa1.y);
        a1[2] = (short)f2bf(wa1.z); a1[3] = (short)f2bf(wa1.w);
        a1[4] = (short)f2bf(wb1.x); a1[5] = (short)f2bf(wb1.y);
        a1[6] = (short)f2bf(wb1.z); a1[7] = (short)f2bf(wb1.w);
        acc0 = __builtin_amdgcn_mfma_f32_16x16x32_bf16(a0, b00, acc0, 0, 0, 0);
        acc1 = __builtin_amdgcn_mfma_f32_16x16x32_bf16(a0, b01, acc1, 0, 0, 0);
        acc2 = __builtin_amdgcn_mfma_f32_16x16x32_bf16(a0, b02, acc2, 0, 0, 0);
        acc3 = __builtin_amdgcn_mfma_f32_16x16x32_bf16(a0, b03, acc3, 0, 0, 0);
        acc0 = __builtin_amdgcn_mfma_f32_16x16x32_bf16(a1, b10, acc0, 0, 0, 0);
        acc1 = __builtin_amdgcn_mfma_f32_16x16x32_bf16(a1, b11, acc1, 0, 0, 0);
        acc2 = __builtin_amdgcn_mfma_f32_16x16x32_bf16(a1, b12, acc2, 0, 0, 0);
        acc3 = __builtin_amdgcn_mfma_f32_16x16x32_bf16(a1, b13, acc3, 0, 0, 0);
    }
    {
        f32x4* dst = (f32x4*)yp;
        dst[(wv * 4 + 0) * 64 + l] = acc0;
        dst[(wv * 4 + 1) * 64 + l] = acc1;
        dst[(wv * 4 + 2) * 64 + l] = acc2;
        dst[(wv * 4 + 3) * 64 + l] = acc3;
    }
    __syncthreads();

    // reduce 16 partials: thread t owns y element (r = t>>6, b = t&63)
    {
        const int r  = tid >> 6;
        const int bb = tid & 63;
        const int btt = bb >> 4;
        const int lii = (bb & 15) | ((r >> 2) << 4);
        const int jq  = r & 3;
        float s = 0.f;
#pragma unroll
        for (int w = 0; w < 16; ++w) s += yp[(((w * 4 + btt) * 64 + lii) << 2) + jq];
        y2[r * 68 + bb] = s;
    }
    __syncthreads();

    // ---------------- phase 2 A-fragments: ya = (-alpha/B) * y, bf16
    const float NC = -0.01f / 64.0f;
    short8 ya0, ya1;
#pragma unroll
    for (int j = 0; j < 8; ++j) {
        ya0[j] = (short)f2bf(NC * y2[lr * 68 + lh * 8 + j]);
        ya1[j] = (short)f2bf(NC * y2[lr * 68 + 32 + lh * 8 + j]);
    }
    __syncthreads();   // protect yp/y2 before dl overwrites them

    // ---------------- phase 2: wave wv owns cols [wv*256, +256), 2 chunks x 128
    constexpr float LRc = 0.001f;
    const short8* xb2v = (const short8*)xb2;
    float* dl = lds + wv * 2112;       // wave-private 16 x 132 f32
    const int c32 = (l & 31) * 4;      // col-in-chunk (float index)
    const int r0 = l >> 5;             // row parity

    for (int c = 0; c < 2; ++c) {
        // 8 jt tiles of d = ya @ xb2  (16 MFMA)
        f32x4 dt[8];
#pragma unroll
        for (int tl = 0; tl < 8; ++tl) {
            const int jt = wv * 16 + c * 8 + tl;
            const int bslot = jt * 128 + l;
            f32x4 d = {0.f, 0.f, 0.f, 0.f};
            d = __builtin_amdgcn_mfma_f32_16x16x32_bf16(ya0, xb2v[bslot], d, 0, 0, 0);
            d = __builtin_amdgcn_mfma_f32_16x16x32_bf16(ya1, xb2v[bslot + 64], d, 0, 0, 0);
            dt[tl] = d;
        }
        // transpose through wave-private LDS (2-way bank alias only)
#pragma unroll
        for (int tl = 0; tl < 8; ++tl)
#pragma unroll
            for (int q = 0; q < 4; ++q)
                dl[(lh * 4 + q) * 132 + tl * 16 + lr] = dt[tl][q];

        // coalesced epilogue: per instr 2 rows x 512B contiguous
        const int colg = wv * 256 + c * 128 + c32;
        float4 wv4[8], gv4[8];
#pragma unroll
        for (int i = 0; i < 8; ++i) {
            const size_t gidx = (size_t)(i0 + r0 + 2 * i) * DIM + colg;
            wv4[i] = ld4(W + gidx);
            gv4[i] = ld4(G + gidx);
        }
#pragma unroll
        for (int i = 0; i < 8; ++i) {
            const float4 dd = ld4(dl + (r0 + 2 * i) * 132 + c32);
            const size_t gidx = (size_t)(i0 + r0 + 2 * i) * DIM + colg;
            float4 o;
            o.x = wv4[i].x - LRc * gv4[i].x + dd.x;
            o.y = wv4[i].y - LRc * gv4[i].y + dd.y;
            o.z = wv4[i].z - LRc * gv4[i].z + dd.z;
            o.w = wv4[i].w - LRc * gv4[i].w + dd.w;
            *reinterpret_cast<float4*>(out + gidx) = o;
        }
    }
}

extern "C" void kernel_launch(void* const* d_in, const int* in_sizes, int n_in,
                              void* d_out, int out_size, void* d_ws, size_t ws_size,
                              hipStream_t stream) {
    const float* W = (const float*)d_in[0];   // weight  (DIM x DIM)
    const float* X = (const float*)d_in[1];   // input_x (BATCH x DIM)
    const float* G = (const float*)d_in[2];   // grad    (DIM x DIM)
    float* out = (float*)d_out;

    unsigned short* xb1 = (unsigned short*)d_ws;               // DIM*BATCH bf16 (512 KB)
    unsigned short* xb2 = xb1 + (size_t)DIM * BATCH;           // BATCH*DIM bf16 (512 KB)

    hipLaunchKernelGGL(k_norm, dim3(BATCH), dim3(256), 0, stream, X, xb1, xb2);
    hipLaunchKernelGGL(k_fused, dim3(DIM / 16), dim3(1024), 0, stream,
                       W, G, xb1, xb2, out);
}